// Round 16
// baseline (807.089 us; speedup 1.0000x reference)
//
#include <hip/hip_runtime.h>
#include <hip/hip_bf16.h>

#define NN 100000
#define NE 600000
#define DD 128
#define NL 3
#define NG 64
#define LN_EPS 1e-5f
#define NTILES 1563
#define GRID_P 512

typedef __attribute__((ext_vector_type(8))) short short8v;
typedef __attribute__((ext_vector_type(8))) unsigned short ushort8v;
typedef __attribute__((ext_vector_type(4))) float f32x4;
typedef unsigned short ushort;
typedef unsigned int uint;

// unpack dword of 2 bf16 (cols c, c+1) to fp32
__device__ inline float2 unpk2(uint u) {
  float2 r;
  r.x = __uint_as_float(u << 16);
  r.y = __uint_as_float(u & 0xffff0000u);
  return r;
}

// RNE pack of two fp32 -> dword of 2 bf16
__device__ inline uint pack2(float a, float b) {
  __hip_bfloat16 ba = __float2bfloat16(a), bb = __float2bfloat16(b);
  return (uint)*(ushort*)&ba | ((uint)*(ushort*)&bb << 16);
}

// ============ CSR build ============
__global__ __launch_bounds__(256)
void count_kernel(const int* __restrict__ dst, int* __restrict__ deg) {
  const int e = blockIdx.x * 256 + threadIdx.x;
  if (e < NE) atomicAdd(&deg[dst[e]], 1);
}

__global__ __launch_bounds__(256)
void scan_a(const int* __restrict__ deg, int* __restrict__ off, int* __restrict__ btot) {
  __shared__ int wsum[4];
  const int t = threadIdx.x, lane = t & 63, wid = t >> 6;
  const int base = blockIdx.x * 1024 + t * 4;
  int4 d = {0, 0, 0, 0};
  if (base < NN) d = *(const int4*)(deg + base);
  const int s0 = d.x, s1 = s0 + d.y, s2 = s1 + d.z, s3 = s2 + d.w;
  int v = s3;
#pragma unroll
  for (int o = 1; o < 64; o <<= 1) { const int u = __shfl_up(v, o); if (lane >= o) v += u; }
  if (lane == 63) wsum[wid] = v;
  __syncthreads();
  if (t == 0) {
    int a = 0;
#pragma unroll
    for (int i = 0; i < 4; ++i) { const int x = wsum[i]; wsum[i] = a; a += x; }
    btot[blockIdx.x] = a;
  }
  __syncthreads();
  const int texcl = wsum[wid] + v - s3;
  if (base < NN) {
    const int4 o4 = {texcl, texcl + s0, texcl + s1, texcl + s2};
    *(int4*)(off + base) = o4;
  }
}

__global__ __launch_bounds__(128)
void scan_b(int* __restrict__ btot, int nb) {
  __shared__ int wsum[2];
  const int t = threadIdx.x, lane = t & 63, wid = t >> 6;
  const int x = (t < nb) ? btot[t] : 0;
  int v = x;
#pragma unroll
  for (int o = 1; o < 64; o <<= 1) { const int u = __shfl_up(v, o); if (lane >= o) v += u; }
  if (lane == 63) wsum[wid] = v;
  __syncthreads();
  if (t == 0) { const int w0 = wsum[0]; wsum[0] = 0; wsum[1] = w0; }
  __syncthreads();
  const int excl = wsum[wid] + v - x;
  if (t < nb) btot[t] = excl;
}

__global__ __launch_bounds__(256)
void scan_c(int* __restrict__ off, const int* __restrict__ btot) {
  const int i = blockIdx.x * 256 + threadIdx.x;
  if (i < NN) off[i] += btot[i >> 10];
}

// fill: atomicAdd turns off[] starts into ends; csr = src per dst bucket
__global__ __launch_bounds__(256)
void fill_kernel(const int* __restrict__ src, const int* __restrict__ dst,
                 int* __restrict__ off, int* __restrict__ csr) {
  const int e = blockIdx.x * 256 + threadIdx.x;
  if (e < NE) {
    const int p = atomicAdd(&off[dst[e]], 1);
    csr[p] = src[e];
  }
}

// ============ weight prep: fragment-ordered bf16 hi/lo ============
__global__ __launch_bounds__(256)
void wprep_kernel(const float* __restrict__ projW, const float* __restrict__ mlpW,
                  ushort* __restrict__ Wp) {
  const int tid = blockIdx.x * 256 + threadIdx.x;   // 8192 total
  const int lane = tid & 63;
  const int fid = tid >> 6;                         // 0..127
  const int mat = fid >> 5;
  const int rem = fid & 31;
  const int kk = rem >> 3, nf = rem & 7;
  const float* W = (mat == 0) ? projW : (mlpW + (size_t)(mat - 1) * DD * DD);
  const int k0 = kk * 32 + (lane >> 4) * 8;
  const int col = nf * 16 + (lane & 15);
  ushort8v hv, lv;
#pragma unroll
  for (int j = 0; j < 8; ++j) {
    const float f = W[(size_t)(k0 + j) * DD + col];
    __hip_bfloat16 bh = __float2bfloat16(f);
    __hip_bfloat16 bl = __float2bfloat16(f - __bfloat162float(bh));
    hv[j] = *(ushort*)&bh;
    lv[j] = *(ushort*)&bl;
  }
  ushort* base = Wp + (size_t)mat * 32768;
  *(ushort8v*)(base + ((size_t)((kk * 8 + nf) * 2 + 0) * 64 + lane) * 8) = hv;
  *(ushort8v*)(base + ((size_t)((kk * 8 + nf) * 2 + 1) * 64 + lane) * 8) = lv;
}

// ============ fused [gather-sum +] GEMM + ReLU [+ LN] ============
// R16: GRID-STRIDE. 512 blocks x 256 threads; each block processes ~3
// 64-row tiles sequentially (R13 body per tile, unchanged). Decouples
// tile count from wave count: R13..R15 all sat at ~100 completed
// waves/us regardless of internals — this launches 2048 waves instead
// of 6252. All LDS wave-private; same-wave DS ops are in-order, so
// cross-tile LDS reuse needs no barrier.
template<int MODE>
__global__ __launch_bounds__(256, 4)
void gemm_node(const float* __restrict__ Xf, const ushort* __restrict__ Hin,
               const int* __restrict__ csr, const int* __restrict__ offE,
               const ushort* __restrict__ Wp, const float* __restrict__ bias,
               const float* __restrict__ lng, const float* __restrict__ lnb,
               ushort* __restrict__ Hout) {
  __align__(16) __shared__ ushort AH[64 * 128];   // 16 KB
  const int t = threadIdx.x, lane = t & 63, w = t >> 6;
  const int q = lane >> 4;          // quarter 0..3
  const int ll = lane & 15;         // chunk index within row
  const uint4* __restrict__ hu4 = (const uint4*)Hin;

  // epilogue constants (tile-invariant)
  const int colb = lane & 15;
  float bias8[8], g8[8], q8[8];
#pragma unroll
  for (int nf = 0; nf < 8; ++nf) {
    bias8[nf] = bias[nf * 16 + colb];
    if (MODE == 1) { g8[nf] = lng[nf * 16 + colb]; q8[nf] = lnb[nf * 16 + colb]; }
  }

#pragma unroll 1
  for (int tile = blockIdx.x; tile < NTILES; tile += GRID_P) {
    const int r0 = tile * 64;
    const int qbase = r0 + w * 16 + q * 4;   // first staged row of this quarter

    // ================= staging (R6 scheme; RNE-bf16 A) =================
    if constexpr (MODE == 1) {
      int offv = 0;
      if (ll < 5) {
        const int gi = qbase - 1 + ll;
        const int gic = gi < 0 ? 0 : (gi > NN - 1 ? NN - 1 : gi);
        offv = (gi < 0) ? 0 : offE[gic];
      }
      int idxA, idxB;
      {
        const int j = ll & 7;
        const int rA = ll >> 3;
        const int a0 = __shfl(offv, q * 16 + rA);
        const int a1 = __shfl(offv, q * 16 + rA + 1);
        int ii = a0 + j;
        int iic = ii < NE ? ii : NE - 1;
        const int cv = csr[iic];
        idxA = (ii < a1) ? cv : NN;
        const int rB = 2 + (ll >> 3);
        const int b0 = __shfl(offv, q * 16 + rB);
        const int b1 = __shfl(offv, q * 16 + rB + 1);
        ii = b0 + j;
        iic = ii < NE ? ii : NE - 1;
        const int cw = csr[iic];
        idxB = (ii < b1) ? cw : NN;
      }

      uint4 gA[9], gB[9];
      auto ISSUE = [&](int s, uint4 (&g)[9]) {
        const int bl = q * 16 + ((s & 1) << 3);
        const int srcv = (s < 2) ? idxA : idxB;
#pragma unroll
        for (int j = 0; j < 8; ++j) {
          const int id = __shfl(srcv, bl + j);
          g[j] = hu4[id * 16 + ll];
        }
        const int v = qbase + s;
        const int sid = (v < NN) ? v : NN;
        g[8] = hu4[sid * 16 + ll];
      };
      auto CONSUME = [&](int s, uint4 (&g)[9]) {
        float4 ev = {0.f, 0.f, 0.f, 0.f}, od = {0.f, 0.f, 0.f, 0.f};
#pragma unroll
        for (int j = 0; j < 9; ++j) {
          const float2 a = unpk2(g[j].x), b = unpk2(g[j].y);
          const float2 c = unpk2(g[j].z), d = unpk2(g[j].w);
          ev.x += a.x; od.x += a.y; ev.y += b.x; od.y += b.y;
          ev.z += c.x; od.z += c.y; ev.w += d.x; od.w += d.y;
        }
        const int i0s = __shfl(offv, q * 16 + s);
        const int i1s = __shfl(offv, q * 16 + s + 1);
        int i = i0s + 8;
#pragma unroll 1
        while (i < i1s) {
#pragma unroll
          for (int jj = 0; jj < 4; ++jj) {
            const int ii = i + jj;
            const int iic = ii < NE ? ii : NE - 1;
            int id = csr[iic];
            id = (ii < i1s) ? id : NN;
            const uint4 gg = hu4[id * 16 + ll];
            const float2 a = unpk2(gg.x), b = unpk2(gg.y);
            const float2 c = unpk2(gg.z), d = unpk2(gg.w);
            ev.x += a.x; od.x += a.y; ev.y += b.x; od.y += b.y;
            ev.z += c.x; od.z += c.y; ev.w += d.x; od.w += d.y;
          }
          i += 4;
        }
        const uint u0 = pack2(ev.x, od.x);
        const uint u1 = pack2(ev.y, od.y);
        const uint u2 = pack2(ev.z, od.z);
        const uint u3 = pack2(ev.w, od.w);
        const int row = w * 16 + q * 4 + s;
        const int uoff = (row * 16 + (ll ^ (row & 7))) * 8;
        *(uint4*)&AH[uoff] = make_uint4(u0, u1, u2, u3);
      };

      ISSUE(0, gA);
      ISSUE(1, gB);
      CONSUME(0, gA);
      ISSUE(2, gA);
      CONSUME(1, gB);
      ISSUE(3, gB);
      CONSUME(2, gA);
      CONSUME(3, gB);
    } else {
      const float4* __restrict__ Xf4 = (const float4*)Xf;
      float4 a0, b0, a1, b1;
      auto LOADX = [&](int s, float4& fa, float4& fb) {
        int v = qbase + s;
        v = v < NN ? v : NN - 1;        // clamp; masked rows never stored
        fa = Xf4[v * 32 + 2 * ll];
        fb = Xf4[v * 32 + 2 * ll + 1];
      };
      auto STOREX = [&](int s, const float4& fa, const float4& fb) {
        const uint u0 = pack2(fa.x, fa.y);
        const uint u1 = pack2(fa.z, fa.w);
        const uint u2 = pack2(fb.x, fb.y);
        const uint u3 = pack2(fb.z, fb.w);
        const int row = w * 16 + q * 4 + s;
        const int uoff = (row * 16 + (ll ^ (row & 7))) * 8;
        *(uint4*)&AH[uoff] = make_uint4(u0, u1, u2, u3);
      };
      LOADX(0, a0, b0);
      LOADX(1, a1, b1);
      STOREX(0, a0, b0);
      LOADX(2, a0, b0);
      STOREX(1, a1, b1);
      LOADX(3, a1, b1);
      STOREX(2, a0, b0);
      STOREX(3, a1, b1);
    }
    // no barrier: each wave reads only its own staged rows below

    // ================= MFMA: Ahi*Bhi + Ahi*Blo =================
    f32x4 accv[8];
#pragma unroll
    for (int nf = 0; nf < 8; ++nf) accv[nf] = (f32x4){0.f, 0.f, 0.f, 0.f};
    const int arow = w * 16 + (lane & 15);
    const int rx = arow & 7;
#pragma unroll
    for (int kk = 0; kk < 4; ++kk) {
      const int aidx = (arow * 16 + ((kk * 4 + q) ^ rx)) * 8;
      const short8v ah = *(const short8v*)&AH[aidx];
#pragma unroll
      for (int nf = 0; nf < 8; ++nf) {
        const ushort* bp = Wp + ((kk * 8 + nf) * 2 * 64 + lane) * 8;
        const short8v bh = *(const short8v*)bp;
        const short8v bl = *(const short8v*)(bp + 512);
        accv[nf] = __builtin_amdgcn_mfma_f32_16x16x32_bf16(ah, bh, accv[nf], 0, 0, 0);
        accv[nf] = __builtin_amdgcn_mfma_f32_16x16x32_bf16(ah, bl, accv[nf], 0, 0, 0);
      }
    }

    // ============ epilogue: regs -> LDS transpose -> coalesced stores ======
    uint* AHu = (uint*)AH;
    const int wbase = w * 1024;               // wave-private: 16 rows x 64 uints
    const bool evl = (colb & 1) == 0;
    const int cc = colb >> 1;
#pragma unroll
    for (int r = 0; r < 4; ++r) {
      float z[8];
      float s = 0.f, s2 = 0.f;
#pragma unroll
      for (int nf = 0; nf < 8; ++nf) {
        z[nf] = fmaxf(accv[nf][r] + bias8[nf], 0.f);
        s += z[nf];
        s2 += z[nf] * z[nf];
      }
      if (MODE == 1) {
#pragma unroll
        for (int o = 1; o < 16; o <<= 1) { s += __shfl_xor(s, o); s2 += __shfl_xor(s2, o); }
        const float mu = s * (1.f / DD);
        const float inv = rsqrtf(s2 * (1.f / DD) - mu * mu + LN_EPS);
#pragma unroll
        for (int nf = 0; nf < 8; ++nf) z[nf] = (z[nf] - mu) * inv * g8[nf] + q8[nf];
      }
      // pack bf16 pairs: TWO lane-uniform shuffles per j
      const int row_local = (lane >> 4) * 4 + r;
      const int swz = (((row_local & 3) ^ (row_local >> 2)) & 3) << 3;
#pragma unroll
      for (int j = 0; j < 4; ++j) {
        const float p_lo = __shfl_xor(z[j], 1);      // partner's z[j]
        const float p_hi = __shfl_xor(z[j + 4], 1);  // partner's z[j+4]
        const uint pk = evl ? pack2(z[j], p_lo) : pack2(p_hi, z[j + 4]);
        const int ucol = (evl ? j * 8 : (j + 4) * 8) + cc;
        AHu[wbase + row_local * 64 + (ucol ^ swz)] = pk;
      }
    }
    // coalesced store: inst m covers 1 KB contiguous (4 rows x 256 B)
    const int lr = lane >> 4;          // row within group of 4
    const int lc = lane & 15;          // 16-B chunk
#pragma unroll
    for (int m = 0; m < 4; ++m) {
      const int row_local = lr + 4 * m;
      const int swz = (((row_local & 3) ^ (row_local >> 2)) & 3) << 3;
      const int grow = r0 + w * 16 + row_local;
      if (grow < NN) {
        const uint4 vv = *(const uint4*)&AHu[wbase + row_local * 64 + ((lc * 4) ^ swz)];
        *(uint4*)(Hout + grow * DD + lc * 8) = vv;
      }
    }
  }
}

// ============ pool (bf16 h, batch_ids sorted; 64 threads, uint loads) ============
__global__ __launch_bounds__(64)
void pool_kernel(const ushort* __restrict__ h, const int* __restrict__ batch,
                 float* __restrict__ sums, float* __restrict__ counts) {
  const int c = threadIdx.x;                 // uint index: cols 2c, 2c+1
  const int base = blockIdx.x * 64;
  const int end = (base + 64 < NN) ? base + 64 : NN;
  const uint* __restrict__ hu = (const uint*)h;
  int cur = batch[base];
  float a0 = 0.f, a1 = 0.f, cnt = 0.f;
  for (int r = base; r < end; ++r) {
    const int g = batch[r];
    if (g != cur) {
      __hip_atomic_fetch_add(&sums[cur * DD + 2 * c], a0, __ATOMIC_RELAXED, __HIP_MEMORY_SCOPE_AGENT);
      __hip_atomic_fetch_add(&sums[cur * DD + 2 * c + 1], a1, __ATOMIC_RELAXED, __HIP_MEMORY_SCOPE_AGENT);
      if (c == 0)
        __hip_atomic_fetch_add(&counts[cur], cnt, __ATOMIC_RELAXED, __HIP_MEMORY_SCOPE_AGENT);
      a0 = 0.f; a1 = 0.f; cnt = 0.f; cur = g;
    }
    const float2 f = unpk2(hu[r * 64 + c]);
    a0 += f.x; a1 += f.y; cnt += 1.f;
  }
  __hip_atomic_fetch_add(&sums[cur * DD + 2 * c], a0, __ATOMIC_RELAXED, __HIP_MEMORY_SCOPE_AGENT);
  __hip_atomic_fetch_add(&sums[cur * DD + 2 * c + 1], a1, __ATOMIC_RELAXED, __HIP_MEMORY_SCOPE_AGENT);
  if (c == 0)
    __hip_atomic_fetch_add(&counts[cur], cnt, __ATOMIC_RELAXED, __HIP_MEMORY_SCOPE_AGENT);
}

__global__ __launch_bounds__(256)
void finalize_kernel(const float* __restrict__ sums, const float* __restrict__ counts,
                     float* __restrict__ out) {
  const int i = blockIdx.x * 256 + threadIdx.x;
  if (i >= NG * DD) return;
  out[i] = sums[i] / fmaxf(counts[i >> 7], 1.f);
}

extern "C" void kernel_launch(void* const* d_in, const int* in_sizes, int n_in,
                              void* d_out, int out_size, void* d_ws, size_t ws_size,
                              hipStream_t stream) {
  const float* x     = (const float*)d_in[0];
  const int*   ei    = (const int*)d_in[1];
  const int*   batch = (const int*)d_in[2];
  const float* projW = (const float*)d_in[3];
  const float* projb = (const float*)d_in[4];
  const float* mlpW  = (const float*)d_in[5];
  const float* mlpb  = (const float*)d_in[6];
  const float* lng   = (const float*)d_in[7];
  const float* lnb   = (const float*)d_in[8];
  float* out = (float*)d_out;

  char* ws = (char*)d_ws;
  ushort* hA    = (ushort*)(ws + 0);           // (NN+1)*256 B = 25,600,256
  ushort* hB    = (ushort*)(ws + 25600256);    // 25,600,256 B
  int*   csr    = (int*)   (ws + 51200512);    //  2,400,000 B
  int*   deg    = (int*)   (ws + 53600512);    //    400,000 B
  int*   off    = (int*)   (ws + 54000512);    //    400,000 B
  int*   btot   = (int*)   (ws + 54400512);    //        512 B
  ushort* Wp    = (ushort*)(ws + 54401024);    //    262,144 B
  float* sums   = (float*) (ws + 54663168);    //     32,768 B
  float* counts = (float*) (ws + 54695936);    //        256 B

  const int* src = ei;
  const int* dst = ei + NE;

  // zero rows (index NN) for the gather zero-target
  hipMemsetAsync(hA + (size_t)NN * DD, 0, DD * sizeof(ushort), stream);
  hipMemsetAsync(hB + (size_t)NN * DD, 0, DD * sizeof(ushort), stream);

  // ---- CSR build ----
  hipMemsetAsync(deg, 0, NN * sizeof(int), stream);
  count_kernel<<<(NE + 255) / 256, 256, 0, stream>>>(dst, deg);
  scan_a<<<(NN + 1023) / 1024, 256, 0, stream>>>(deg, off, btot);
  scan_b<<<1, 128, 0, stream>>>(btot, (NN + 1023) / 1024);
  scan_c<<<(NN + 255) / 256, 256, 0, stream>>>(off, btot);
  fill_kernel<<<(NE + 255) / 256, 256, 0, stream>>>(src, dst, off, csr);

  // ---- weight prep ----
  wprep_kernel<<<32, 256, 0, stream>>>(projW, mlpW, Wp);

  // h = relu(x @ projW + projb) -> bf16
  gemm_node<0><<<GRID_P, 256, 0, stream>>>(
      x, nullptr, nullptr, nullptr, Wp, projb, nullptr, nullptr, hA);

  // 3 fused GIN layers, ping-pong hA/hB
  ushort* hin = hA;
  ushort* hout = hB;
  for (int l = 0; l < NL; ++l) {
    gemm_node<1><<<GRID_P, 256, 0, stream>>>(
        nullptr, hin, csr, off, Wp + (size_t)(1 + l) * 32768,
        mlpb + (size_t)l * DD, lng + (size_t)l * DD, lnb + (size_t)l * DD, hout);
    ushort* tmp = hin; hin = hout; hout = tmp;
  }

  hipMemsetAsync(sums, 0, (size_t)(NG * DD + NG) * sizeof(float), stream);
  pool_kernel<<<(NN + 63) / 64, 64, 0, stream>>>(hin, batch, sums, counts);
  finalize_kernel<<<(NG * DD + 255) / 256, 256, 0, stream>>>(sums, counts, out);
}

// Round 17
// 260.313 us; speedup vs baseline: 3.1005x; 3.1005x over previous
//
#include <hip/hip_runtime.h>
#include <hip/hip_bf16.h>

#define NN 100000
#define NE 600000
#define DD 128
#define NL 3
#define NG 64
#define LN_EPS 1e-5f

typedef __attribute__((ext_vector_type(8))) short short8v;
typedef __attribute__((ext_vector_type(8))) unsigned short ushort8v;
typedef __attribute__((ext_vector_type(4))) float f32x4;
typedef unsigned short ushort;
typedef unsigned int uint;

// unpack dword of 2 bf16 (cols c, c+1) to fp32
__device__ inline float2 unpk2(uint u) {
  float2 r;
  r.x = __uint_as_float(u << 16);
  r.y = __uint_as_float(u & 0xffff0000u);
  return r;
}

// RNE pack of two fp32 -> dword of 2 bf16
__device__ inline uint pack2(float a, float b) {
  __hip_bfloat16 ba = __float2bfloat16(a), bb = __float2bfloat16(b);
  return (uint)*(ushort*)&ba | ((uint)*(ushort*)&bb << 16);
}

// ============ CSR build ============
__global__ __launch_bounds__(256)
void count_kernel(const int* __restrict__ dst, int* __restrict__ deg) {
  const int e = blockIdx.x * 256 + threadIdx.x;
  if (e < NE) atomicAdd(&deg[dst[e]], 1);
}

__global__ __launch_bounds__(256)
void scan_a(const int* __restrict__ deg, int* __restrict__ off, int* __restrict__ btot) {
  __shared__ int wsum[4];
  const int t = threadIdx.x, lane = t & 63, wid = t >> 6;
  const int base = blockIdx.x * 1024 + t * 4;
  int4 d = {0, 0, 0, 0};
  if (base < NN) d = *(const int4*)(deg + base);
  const int s0 = d.x, s1 = s0 + d.y, s2 = s1 + d.z, s3 = s2 + d.w;
  int v = s3;
#pragma unroll
  for (int o = 1; o < 64; o <<= 1) { const int u = __shfl_up(v, o); if (lane >= o) v += u; }
  if (lane == 63) wsum[wid] = v;
  __syncthreads();
  if (t == 0) {
    int a = 0;
#pragma unroll
    for (int i = 0; i < 4; ++i) { const int x = wsum[i]; wsum[i] = a; a += x; }
    btot[blockIdx.x] = a;
  }
  __syncthreads();
  const int texcl = wsum[wid] + v - s3;
  if (base < NN) {
    const int4 o4 = {texcl, texcl + s0, texcl + s1, texcl + s2};
    *(int4*)(off + base) = o4;
  }
}

__global__ __launch_bounds__(128)
void scan_b(int* __restrict__ btot, int nb) {
  __shared__ int wsum[2];
  const int t = threadIdx.x, lane = t & 63, wid = t >> 6;
  const int x = (t < nb) ? btot[t] : 0;
  int v = x;
#pragma unroll
  for (int o = 1; o < 64; o <<= 1) { const int u = __shfl_up(v, o); if (lane >= o) v += u; }
  if (lane == 63) wsum[wid] = v;
  __syncthreads();
  if (t == 0) { const int w0 = wsum[0]; wsum[0] = 0; wsum[1] = w0; }
  __syncthreads();
  const int excl = wsum[wid] + v - x;
  if (t < nb) btot[t] = excl;
}

__global__ __launch_bounds__(256)
void scan_c(int* __restrict__ off, const int* __restrict__ btot) {
  const int i = blockIdx.x * 256 + threadIdx.x;
  if (i < NN) off[i] += btot[i >> 10];
}

// fill: atomicAdd turns off[] starts into ends; csr = src per dst bucket
__global__ __launch_bounds__(256)
void fill_kernel(const int* __restrict__ src, const int* __restrict__ dst,
                 int* __restrict__ off, int* __restrict__ csr) {
  const int e = blockIdx.x * 256 + threadIdx.x;
  if (e < NE) {
    const int p = atomicAdd(&off[dst[e]], 1);
    csr[p] = src[e];
  }
}

// ============ weight prep: fragment-ordered bf16 hi/lo ============
__global__ __launch_bounds__(256)
void wprep_kernel(const float* __restrict__ projW, const float* __restrict__ mlpW,
                  ushort* __restrict__ Wp) {
  const int tid = blockIdx.x * 256 + threadIdx.x;   // 8192 total
  const int lane = tid & 63;
  const int fid = tid >> 6;                         // 0..127
  const int mat = fid >> 5;
  const int rem = fid & 31;
  const int kk = rem >> 3, nf = rem & 7;
  const float* W = (mat == 0) ? projW : (mlpW + (size_t)(mat - 1) * DD * DD);
  const int k0 = kk * 32 + (lane >> 4) * 8;
  const int col = nf * 16 + (lane & 15);
  ushort8v hv, lv;
#pragma unroll
  for (int j = 0; j < 8; ++j) {
    const float f = W[(size_t)(k0 + j) * DD + col];
    __hip_bfloat16 bh = __float2bfloat16(f);
    __hip_bfloat16 bl = __float2bfloat16(f - __bfloat162float(bh));
    hv[j] = *(ushort*)&bh;
    lv[j] = *(ushort*)&bl;
  }
  ushort* base = Wp + (size_t)mat * 32768;
  *(ushort8v*)(base + ((size_t)((kk * 8 + nf) * 2 + 0) * 64 + lane) * 8) = hv;
  *(ushort8v*)(base + ((size_t)((kk * 8 + nf) * 2 + 1) * 64 + lane) * 8) = lv;
}

// ============ fused [gather-sum +] GEMM + ReLU [+ LN] ============
// R17 = R13 verbatim (best measured: 261 us). Block 256 = 4 waves,
// tile 64 rows x 128 cols, wave-private end-to-end, no barriers, 16 KB LDS.
template<int MODE>
__global__ __launch_bounds__(256, 4)
void gemm_node(const float* __restrict__ Xf, const ushort* __restrict__ Hin,
               const int* __restrict__ csr, const int* __restrict__ offE,
               const ushort* __restrict__ Wp, const float* __restrict__ bias,
               const float* __restrict__ lng, const float* __restrict__ lnb,
               ushort* __restrict__ Hout) {
  __align__(16) __shared__ ushort AH[64 * 128];   // 16 KB
  const int t = threadIdx.x, lane = t & 63, w = t >> 6;
  const int q = lane >> 4;          // quarter 0..3
  const int ll = lane & 15;         // chunk index within row
  const int r0 = blockIdx.x * 64;
  const int qbase = r0 + w * 16 + q * 4;   // first staged row of this quarter
  const uint4* __restrict__ hu4 = (const uint4*)Hin;

  // ================= staging (R6 scheme; RNE-bf16 A) =================
  if constexpr (MODE == 1) {
    int offv = 0;
    if (ll < 5) {
      const int gi = qbase - 1 + ll;
      const int gic = gi < 0 ? 0 : (gi > NN - 1 ? NN - 1 : gi);
      offv = (gi < 0) ? 0 : offE[gic];
    }
    int idxA, idxB;
    {
      const int j = ll & 7;
      const int rA = ll >> 3;
      const int a0 = __shfl(offv, q * 16 + rA);
      const int a1 = __shfl(offv, q * 16 + rA + 1);
      int ii = a0 + j;
      int iic = ii < NE ? ii : NE - 1;
      const int cv = csr[iic];
      idxA = (ii < a1) ? cv : NN;
      const int rB = 2 + (ll >> 3);
      const int b0 = __shfl(offv, q * 16 + rB);
      const int b1 = __shfl(offv, q * 16 + rB + 1);
      ii = b0 + j;
      iic = ii < NE ? ii : NE - 1;
      const int cw = csr[iic];
      idxB = (ii < b1) ? cw : NN;
    }

    uint4 gA[9], gB[9];
    auto ISSUE = [&](int s, uint4 (&g)[9]) {
      const int bl = q * 16 + ((s & 1) << 3);
      const int srcv = (s < 2) ? idxA : idxB;
#pragma unroll
      for (int j = 0; j < 8; ++j) {
        const int id = __shfl(srcv, bl + j);
        g[j] = hu4[id * 16 + ll];
      }
      const int v = qbase + s;
      const int sid = (v < NN) ? v : NN;
      g[8] = hu4[sid * 16 + ll];
    };
    auto CONSUME = [&](int s, uint4 (&g)[9]) {
      float4 ev = {0.f, 0.f, 0.f, 0.f}, od = {0.f, 0.f, 0.f, 0.f};
#pragma unroll
      for (int j = 0; j < 9; ++j) {
        const float2 a = unpk2(g[j].x), b = unpk2(g[j].y);
        const float2 c = unpk2(g[j].z), d = unpk2(g[j].w);
        ev.x += a.x; od.x += a.y; ev.y += b.x; od.y += b.y;
        ev.z += c.x; od.z += c.y; ev.w += d.x; od.w += d.y;
      }
      const int i0s = __shfl(offv, q * 16 + s);
      const int i1s = __shfl(offv, q * 16 + s + 1);
      int i = i0s + 8;
#pragma unroll 1
      while (i < i1s) {
#pragma unroll
        for (int jj = 0; jj < 4; ++jj) {
          const int ii = i + jj;
          const int iic = ii < NE ? ii : NE - 1;
          int id = csr[iic];
          id = (ii < i1s) ? id : NN;
          const uint4 gg = hu4[id * 16 + ll];
          const float2 a = unpk2(gg.x), b = unpk2(gg.y);
          const float2 c = unpk2(gg.z), d = unpk2(gg.w);
          ev.x += a.x; od.x += a.y; ev.y += b.x; od.y += b.y;
          ev.z += c.x; od.z += c.y; ev.w += d.x; od.w += d.y;
        }
        i += 4;
      }
      const uint u0 = pack2(ev.x, od.x);
      const uint u1 = pack2(ev.y, od.y);
      const uint u2 = pack2(ev.z, od.z);
      const uint u3 = pack2(ev.w, od.w);
      const int row = w * 16 + q * 4 + s;
      const int uoff = (row * 16 + (ll ^ (row & 7))) * 8;
      *(uint4*)&AH[uoff] = make_uint4(u0, u1, u2, u3);
    };

    ISSUE(0, gA);
    ISSUE(1, gB);
    CONSUME(0, gA);
    ISSUE(2, gA);
    CONSUME(1, gB);
    ISSUE(3, gB);
    CONSUME(2, gA);
    CONSUME(3, gB);
  } else {
    const float4* __restrict__ Xf4 = (const float4*)Xf;
    float4 a0, b0, a1, b1;
    auto LOADX = [&](int s, float4& fa, float4& fb) {
      int v = qbase + s;
      v = v < NN ? v : NN - 1;        // clamp; masked rows never stored
      fa = Xf4[v * 32 + 2 * ll];
      fb = Xf4[v * 32 + 2 * ll + 1];
    };
    auto STOREX = [&](int s, const float4& fa, const float4& fb) {
      const uint u0 = pack2(fa.x, fa.y);
      const uint u1 = pack2(fa.z, fa.w);
      const uint u2 = pack2(fb.x, fb.y);
      const uint u3 = pack2(fb.z, fb.w);
      const int row = w * 16 + q * 4 + s;
      const int uoff = (row * 16 + (ll ^ (row & 7))) * 8;
      *(uint4*)&AH[uoff] = make_uint4(u0, u1, u2, u3);
    };
    LOADX(0, a0, b0);
    LOADX(1, a1, b1);
    STOREX(0, a0, b0);
    LOADX(2, a0, b0);
    STOREX(1, a1, b1);
    LOADX(3, a1, b1);
    STOREX(2, a0, b0);
    STOREX(3, a1, b1);
  }
  // no barrier: each wave reads only its own staged rows below

  // ================= MFMA: Ahi*Bhi + Ahi*Blo =================
  f32x4 accv[8];
#pragma unroll
  for (int nf = 0; nf < 8; ++nf) accv[nf] = (f32x4){0.f, 0.f, 0.f, 0.f};
  const int arow = w * 16 + (lane & 15);
  const int rx = arow & 7;
#pragma unroll
  for (int kk = 0; kk < 4; ++kk) {
    short8v B[16];
#pragma unroll
    for (int nf = 0; nf < 8; ++nf) {
      const ushort* bp = Wp + ((kk * 8 + nf) * 2 * 64 + lane) * 8;
      B[2 * nf] = *(const short8v*)bp;
      B[2 * nf + 1] = *(const short8v*)(bp + 512);
    }
    const int aidx = (arow * 16 + ((kk * 4 + q) ^ rx)) * 8;
    const short8v ah = *(const short8v*)&AH[aidx];
#pragma unroll
    for (int nf = 0; nf < 8; ++nf) {
      accv[nf] = __builtin_amdgcn_mfma_f32_16x16x32_bf16(ah, B[2 * nf], accv[nf], 0, 0, 0);
      accv[nf] = __builtin_amdgcn_mfma_f32_16x16x32_bf16(ah, B[2 * nf + 1], accv[nf], 0, 0, 0);
    }
  }

  // ================= epilogue: regs -> LDS transpose -> coalesced stores ====
  const int colb = lane & 15;
  float bias8[8], g8[8], q8[8];
#pragma unroll
  for (int nf = 0; nf < 8; ++nf) {
    bias8[nf] = bias[nf * 16 + colb];
    if (MODE == 1) { g8[nf] = lng[nf * 16 + colb]; q8[nf] = lnb[nf * 16 + colb]; }
  }

  uint* AHu = (uint*)AH;
  const int wbase = w * 1024;               // wave-private: 16 rows x 64 uints
  const bool evl = (colb & 1) == 0;
  const int cc = colb >> 1;
#pragma unroll
  for (int r = 0; r < 4; ++r) {
    float z[8];
    float s = 0.f, s2 = 0.f;
#pragma unroll
    for (int nf = 0; nf < 8; ++nf) {
      z[nf] = fmaxf(accv[nf][r] + bias8[nf], 0.f);
      s += z[nf];
      s2 += z[nf] * z[nf];
    }
    if (MODE == 1) {
#pragma unroll
      for (int o = 1; o < 16; o <<= 1) { s += __shfl_xor(s, o); s2 += __shfl_xor(s2, o); }
      const float mu = s * (1.f / DD);
      const float inv = rsqrtf(s2 * (1.f / DD) - mu * mu + LN_EPS);
#pragma unroll
      for (int nf = 0; nf < 8; ++nf) z[nf] = (z[nf] - mu) * inv * g8[nf] + q8[nf];
    }
    // pack bf16 pairs: TWO lane-uniform shuffles per j
    const int row_local = (lane >> 4) * 4 + r;
    const int swz = (((row_local & 3) ^ (row_local >> 2)) & 3) << 3;
#pragma unroll
    for (int j = 0; j < 4; ++j) {
      const float p_lo = __shfl_xor(z[j], 1);      // partner's z[j]
      const float p_hi = __shfl_xor(z[j + 4], 1);  // partner's z[j+4]
      const uint pk = evl ? pack2(z[j], p_lo) : pack2(p_hi, z[j + 4]);
      const int ucol = (evl ? j * 8 : (j + 4) * 8) + cc;
      AHu[wbase + row_local * 64 + (ucol ^ swz)] = pk;
    }
  }
  // coalesced store: inst m covers 1 KB contiguous (4 rows x 256 B)
  const int lr = lane >> 4;          // row within group of 4
  const int lc = lane & 15;          // 16-B chunk
#pragma unroll
  for (int m = 0; m < 4; ++m) {
    const int row_local = lr + 4 * m;
    const int swz = (((row_local & 3) ^ (row_local >> 2)) & 3) << 3;
    const int grow = r0 + w * 16 + row_local;
    if (grow < NN) {
      const uint4 vv = *(const uint4*)&AHu[wbase + row_local * 64 + ((lc * 4) ^ swz)];
      *(uint4*)(Hout + grow * DD + lc * 8) = vv;
    }
  }
}

// ============ pool (bf16 h, batch_ids sorted; 64 threads, uint loads) ============
__global__ __launch_bounds__(64)
void pool_kernel(const ushort* __restrict__ h, const int* __restrict__ batch,
                 float* __restrict__ sums, float* __restrict__ counts) {
  const int c = threadIdx.x;                 // uint index: cols 2c, 2c+1
  const int base = blockIdx.x * 64;
  const int end = (base + 64 < NN) ? base + 64 : NN;
  const uint* __restrict__ hu = (const uint*)h;
  int cur = batch[base];
  float a0 = 0.f, a1 = 0.f, cnt = 0.f;
  for (int r = base; r < end; ++r) {
    const int g = batch[r];
    if (g != cur) {
      __hip_atomic_fetch_add(&sums[cur * DD + 2 * c], a0, __ATOMIC_RELAXED, __HIP_MEMORY_SCOPE_AGENT);
      __hip_atomic_fetch_add(&sums[cur * DD + 2 * c + 1], a1, __ATOMIC_RELAXED, __HIP_MEMORY_SCOPE_AGENT);
      if (c == 0)
        __hip_atomic_fetch_add(&counts[cur], cnt, __ATOMIC_RELAXED, __HIP_MEMORY_SCOPE_AGENT);
      a0 = 0.f; a1 = 0.f; cnt = 0.f; cur = g;
    }
    const float2 f = unpk2(hu[r * 64 + c]);
    a0 += f.x; a1 += f.y; cnt += 1.f;
  }
  __hip_atomic_fetch_add(&sums[cur * DD + 2 * c], a0, __ATOMIC_RELAXED, __HIP_MEMORY_SCOPE_AGENT);
  __hip_atomic_fetch_add(&sums[cur * DD + 2 * c + 1], a1, __ATOMIC_RELAXED, __HIP_MEMORY_SCOPE_AGENT);
  if (c == 0)
    __hip_atomic_fetch_add(&counts[cur], cnt, __ATOMIC_RELAXED, __HIP_MEMORY_SCOPE_AGENT);
}

__global__ __launch_bounds__(256)
void finalize_kernel(const float* __restrict__ sums, const float* __restrict__ counts,
                     float* __restrict__ out) {
  const int i = blockIdx.x * 256 + threadIdx.x;
  if (i >= NG * DD) return;
  out[i] = sums[i] / fmaxf(counts[i >> 7], 1.f);
}

extern "C" void kernel_launch(void* const* d_in, const int* in_sizes, int n_in,
                              void* d_out, int out_size, void* d_ws, size_t ws_size,
                              hipStream_t stream) {
  const float* x     = (const float*)d_in[0];
  const int*   ei    = (const int*)d_in[1];
  const int*   batch = (const int*)d_in[2];
  const float* projW = (const float*)d_in[3];
  const float* projb = (const float*)d_in[4];
  const float* mlpW  = (const float*)d_in[5];
  const float* mlpb  = (const float*)d_in[6];
  const float* lng   = (const float*)d_in[7];
  const float* lnb   = (const float*)d_in[8];
  float* out = (float*)d_out;

  char* ws = (char*)d_ws;
  ushort* hA    = (ushort*)(ws + 0);           // (NN+1)*256 B = 25,600,256
  ushort* hB    = (ushort*)(ws + 25600256);    // 25,600,256 B
  int*   csr    = (int*)   (ws + 51200512);    //  2,400,000 B
  int*   deg    = (int*)   (ws + 53600512);    //    400,000 B
  int*   off    = (int*)   (ws + 54000512);    //    400,000 B
  int*   btot   = (int*)   (ws + 54400512);    //        512 B
  ushort* Wp    = (ushort*)(ws + 54401024);    //    262,144 B
  float* sums   = (float*) (ws + 54663168);    //     32,768 B
  float* counts = (float*) (ws + 54695936);    //        256 B

  const int* src = ei;
  const int* dst = ei + NE;

  // zero rows (index NN) for the gather zero-target
  hipMemsetAsync(hA + (size_t)NN * DD, 0, DD * sizeof(ushort), stream);
  hipMemsetAsync(hB + (size_t)NN * DD, 0, DD * sizeof(ushort), stream);

  // ---- CSR build ----
  hipMemsetAsync(deg, 0, NN * sizeof(int), stream);
  count_kernel<<<(NE + 255) / 256, 256, 0, stream>>>(dst, deg);
  scan_a<<<(NN + 1023) / 1024, 256, 0, stream>>>(deg, off, btot);
  scan_b<<<1, 128, 0, stream>>>(btot, (NN + 1023) / 1024);
  scan_c<<<(NN + 255) / 256, 256, 0, stream>>>(off, btot);
  fill_kernel<<<(NE + 255) / 256, 256, 0, stream>>>(src, dst, off, csr);

  // ---- weight prep ----
  wprep_kernel<<<32, 256, 0, stream>>>(projW, mlpW, Wp);

  const int gemm_blocks = (NN + 63) / 64;   // 1563

  // h = relu(x @ projW + projb) -> bf16
  gemm_node<0><<<gemm_blocks, 256, 0, stream>>>(
      x, nullptr, nullptr, nullptr, Wp, projb, nullptr, nullptr, hA);

  // 3 fused GIN layers, ping-pong hA/hB
  ushort* hin = hA;
  ushort* hout = hB;
  for (int l = 0; l < NL; ++l) {
    gemm_node<1><<<gemm_blocks, 256, 0, stream>>>(
        nullptr, hin, csr, off, Wp + (size_t)(1 + l) * 32768,
        mlpb + (size_t)l * DD, lng + (size_t)l * DD, lnb + (size_t)l * DD, hout);
    ushort* tmp = hin; hin = hout; hout = tmp;
  }

  hipMemsetAsync(sums, 0, (size_t)(NG * DD + NG) * sizeof(float), stream);
  pool_kernel<<<(NN + 63) / 64, 64, 0, stream>>>(hin, batch, sums, counts);
  finalize_kernel<<<(NG * DD + 255) / 256, 256, 0, stream>>>(sums, counts, out);
}